// Round 4
// baseline (847.463 us; speedup 1.0000x reference)
//
#include <hip/hip_runtime.h>
#include <cstdint>

#define BTOT 4096
#define NBLK 1366   // ceil(4096/3)

// One wave per block. Lanes 0..59 = 3 batch groups x 20 neurons; lanes 60..63 idle dups.
// LDS: only LUT[4][32][20] (nibble-sums of W2 columns, pre-scaled by 0.5) + 64 floats
// for the epilogue exchange. x is loaded global->VGPR through a 3-deep register
// pipeline (3 buffers x 14 float4 = 168 VGPR): load for t+3 issues while t, t+1, t+2
// compute => ~2 tc4-groups (>1000 cy) of latency coverage. __launch_bounds__(64,2)
// caps VGPR at 256 so 2 waves/SIMD (8 blocks/CU) always fit (>= 5.34 needed).
__global__ __launch_bounds__(64, 2)
void snn_kernel(const float* __restrict__ x, const float* __restrict__ W1,
                const float* __restrict__ W2, const float* __restrict__ W3,
                float* __restrict__ out) {
  __shared__ __align__(16) float lutf[2560 + 64];
  const int lane = threadIdx.x;
  const int bid  = blockIdx.x;

  // Build LUT: lutf[q*640 + m*20 + i] = 0.5 * sum_{k: m has bit k} W2[i][5*q+k]
  for (int idx = lane; idx < 2560; idx += 64) {
    int q   = idx / 640;
    int rem = idx - q * 640;
    int m   = rem / 20;
    int i   = rem - m * 20;
    float s = 0.f;
    #pragma unroll
    for (int k = 0; k < 5; ++k)
      if (m & (1 << k)) s += W2[i * 20 + q * 5 + k];
    lutf[idx] = 0.5f * s;
  }

  const int  g3     = lane / 20;            // 0..3
  const int  g      = g3 < 3 ? g3 : 2;      // clamp idle lanes onto group 2
  const int  i      = lane - g * 20;        // 0..19 (20..23 for idle lanes)
  const int  i19    = i < 20 ? i : 19;
  const bool active = (g3 < 3);
  const long b      = (long)bid * 3 + g;
  const bool bvalid = (b < BTOT);
  const long bc     = bvalid ? b : (BTOT - 1);

  // W1 row, pre-scaled by 0.5 (folds the /tau).
  float w1r[14];
  #pragma unroll
  for (int l = 0; l < 14; ++l) w1r[l] = 0.5f * W1[i19 * 14 + l];

  float v1 = 0.f, v2 = 0.f, aacc = 0.f;
  const unsigned sh = 20u * (unsigned)g;

  // Row l of this group's batch starts at float4 index l*250.
  const float4* __restrict__ xr0 = (const float4*)(x + bc * 14000);

  __syncthreads();  // LUT ready

  float4 xa[14], xb[14], xc[14];

#define LOADBUF(BUF, T)                                        \
  do {                                                         \
    int _t = (T); if (_t > 249) _t = 249;                      \
    _Pragma("unroll")                                          \
    for (int _l = 0; _l < 14; ++_l) BUF[_l] = xr0[_l * 250 + _t]; \
  } while (0)

  auto step4 = [&](const float4 (&xr)[14]) {
    // h1 for 4 timesteps: 4 independent fma chains (ILP).
    float ha = 0.f, hb = 0.f, hc = 0.f, hd = 0.f;
    #pragma unroll
    for (int l = 0; l < 14; ++l) {
      const float w = w1r[l];
      ha = fmaf(w, xr[l].x, ha);
      hb = fmaf(w, xr[l].y, hb);
      hc = fmaf(w, xr[l].z, hc);
      hd = fmaf(w, xr[l].w, hd);
    }
    float h1v[4] = {ha, hb, hc, hd};

    // LIF layer 1 + ballots (serial v1 chain, no LDS).
    unsigned mk[4];
    #pragma unroll
    for (int dt = 0; dt < 4; ++dt) {
      v1 = fmaf(v1, 0.5f, h1v[dt]);   // v' = v/2 + h/2 (W1 pre-scaled)
      const bool sp1 = (v1 >= 5.0f);
      v1 = sp1 ? 0.f : v1;
      mk[dt] = (unsigned)(__ballot(sp1) >> sh);  // bits >19 junk; bfe masks
    }

    // All 16 LUT loads issued back-to-back (pipelined lgkmcnt).
    float hq[16];
    #pragma unroll
    for (int dt = 0; dt < 4; ++dt) {
      #pragma unroll
      for (int q = 0; q < 4; ++q)
        hq[dt * 4 + q] = lutf[q * 640 + ((mk[dt] >> (5 * q)) & 31u) * 20 + i19];
    }

    // LIF layer 2 + layer-3 closed-form accumulator.
    #pragma unroll
    for (int dt = 0; dt < 4; ++dt) {
      const float h2 = (hq[dt * 4 + 0] + hq[dt * 4 + 1]) +
                       (hq[dt * 4 + 2] + hq[dt * 4 + 3]);  // already *0.5
      v2 = fmaf(v2, 0.5f, h2);
      const bool sp2 = (v2 >= 5.0f);
      v2 = sp2 ? 0.f : v2;
      aacc = fmaf(aacc, 0.5f, sp2 ? 0.5f : 0.f);
    }
  };

  // 3-deep register pipeline over 250 tc4-groups: 83 x 3 + 1 epilogue.
  LOADBUF(xa, 0);
  LOADBUF(xb, 1);
  LOADBUF(xc, 2);
  for (int t4 = 0; t4 < 249; t4 += 3) {
    step4(xa); LOADBUF(xa, t4 + 3);
    step4(xb); LOADBUF(xb, t4 + 4);
    step4(xc); LOADBUF(xc, t4 + 5);
  }
  step4(xa);  // t4 = 249 (loaded on the last loop iteration)

  // Epilogue: out[b][k] = exp( sum_j W3[k][j] * a[j] )
  __syncthreads();
  if (active) lutf[2560 + g * 20 + i] = aacc;
  __syncthreads();
  if (active && bvalid) {
    float ar[20];
    #pragma unroll
    for (int j = 0; j < 20; ++j) ar[j] = lutf[2560 + g * 20 + j];
    for (int q = 0; q < 25; ++q) {
      const int k = i + 20 * q;
      float acc = 0.f;
      #pragma unroll
      for (int j = 0; j < 20; ++j) acc = fmaf(W3[k * 20 + j], ar[j], acc);
      out[b * 500 + k] = expf(acc);
    }
  }
}

extern "C" void kernel_launch(void* const* d_in, const int* in_sizes, int n_in,
                              void* d_out, int out_size, void* d_ws, size_t ws_size,
                              hipStream_t stream) {
  const float* x  = (const float*)d_in[0];
  const float* W1 = (const float*)d_in[1];
  const float* W2 = (const float*)d_in[2];
  const float* W3 = (const float*)d_in[3];
  float* out = (float*)d_out;
  snn_kernel<<<dim3(NBLK), dim3(64), 0, stream>>>(x, W1, W2, W3, out);
}